// Round 4
// baseline (858.480 us; speedup 1.0000x reference)
//
#include <hip/hip_runtime.h>

// Submanifold sparse conv — single fused dispatch, 1024 blocks x 256 thr
// (4 blocks/CU co-resident, 16 waves/CU: 4x R3's occupancy).
// Phases (two-level grid barriers between):
//   A: zero grid slices; block0 zeroes barrier/cnt lines, publishes MAGIC gate
//   B: build voxel grid: atomicMax(grid[key], n-i)  (min-index dup resolution)
//   C: each point probes its 27 neighbors (plain cacheable loads, MLP);
//      o==13 -> rep[pt]; else wave-aggregated append (j,pt) to list[o]
//   D: center: out[pt*32+cout] = feat[rep[pt]] . W13col   (plain stores, W in VGPRs)
//   E: drain 26 lists: W[o] column in 32 VGPRs, half-wave per pair,
//      float4 feature broadcasts, atomicAdd into out.
// R3 lesson: grid-barrier co-residency at 2 blocks/CU (2 waves/SIMD) left the
// kernel 97% stalled (VALUBusy 2.9%); per-access agent atomics bypassed L1.
// Fix: 4 blocks/CU + plain loads, coherence via barrier release/acquire only.

#define GRID_B 130
#define GRID_CELLS 2197000
#define GRID_PAD_I 2197056            // padded to int4 multiple
#define C 32
#define N_CAP 8192                    // per-offset list cap (expected ~4.7k)
#define NBLK 1024
#define NTHR 256
#define NT (NBLK * NTHR)              // 262144
#define GROUPS 32
#define BLK_PER_GROUP (NBLK / GROUPS) // 32
#define LSTR 32                       // 32 ints = 128B: one L2 line per counter

// ws layout (int units)
#define GATE_I  GRID_PAD_I
#define GRP_I   (GATE_I + LSTR)
#define GLOB_I  (GRP_I + GROUPS * LSTR)
#define REL_I   (GLOB_I + LSTR)
#define CNT_I   (REL_I + GROUPS * LSTR)
#define REP_I   (CNT_I + 27 * LSTR)
#define LISTS_I (REP_I + 100032)      // 8B-aligned; lists end ~10.5 MiB total
#define MAGIC 0x5AD0C0DE

#define AR __ATOMIC_RELAXED
#define SC __HIP_MEMORY_SCOPE_AGENT

__device__ __forceinline__ void gbar(int* ws_i, int k) {
    __threadfence();
    __syncthreads();
    if (threadIdx.x == 0) {
        const int g = blockIdx.x / BLK_PER_GROUP;
        int a = __hip_atomic_fetch_add(ws_i + GRP_I + g * LSTR, 1,
                                       __ATOMIC_ACQ_REL, SC);
        if (a == k * BLK_PER_GROUP - 1) {
            int b = __hip_atomic_fetch_add(ws_i + GLOB_I, 1, __ATOMIC_ACQ_REL, SC);
            if (b == k * GROUPS - 1) {
                __threadfence();                       // release for all prior writes
                for (int i = 0; i < GROUPS; ++i)
                    __hip_atomic_store(ws_i + REL_I + i * LSTR, k, AR, SC);
            }
        }
        while (__hip_atomic_load(ws_i + REL_I + g * LSTR, __ATOMIC_ACQUIRE, SC) < k)
            __builtin_amdgcn_s_sleep(2);
    }
    __syncthreads();
}

__global__ __launch_bounds__(NTHR, 4)
void fused_kernel(const float* __restrict__ feat,
                  const int* __restrict__ pos,
                  const float* __restrict__ w,
                  int* __restrict__ ws_i,
                  float* __restrict__ out, int n) {
    const int tid = blockIdx.x * NTHR + threadIdx.x;
    const int lane = threadIdx.x & 63;

    // ---- Phase A: zero grid; block0 inits barrier area + gate ----
    {
        int4 z4 = make_int4(0, 0, 0, 0);
        int4* g4 = (int4*)ws_i;
        for (int i = tid; i < GRID_PAD_I / 4; i += NT) g4[i] = z4;
        if (blockIdx.x == 0) {
            for (int i = threadIdx.x; i < REP_I - GRP_I; i += NTHR)
                ws_i[GRP_I + i] = 0;                   // grp, glob, rel, cnt lines
            __syncthreads();
            if (threadIdx.x == 0) {
                __threadfence();
                __hip_atomic_store(ws_i + GATE_I, MAGIC, __ATOMIC_RELEASE, SC);
            }
        }
        if (threadIdx.x == 0) {
            while (__hip_atomic_load(ws_i + GATE_I, __ATOMIC_ACQUIRE, SC) != MAGIC)
                __builtin_amdgcn_s_sleep(2);
        }
        __syncthreads();
    }
    gbar(ws_i, 1);

    // ---- Phase B: build voxel grid ----
    const bool active = tid < n;
    int px = 0, py = 0, pz = 0;
    if (active) {
        px = pos[3 * tid + 0] + 1;
        py = pos[3 * tid + 1] + 1;
        pz = pos[3 * tid + 2] + 1;
        __hip_atomic_fetch_max(ws_i + (px * GRID_B + py) * GRID_B + pz,
                               n - tid, AR, SC);       // max(n-i) == min index
    }
    gbar(ws_i, 2);

    // ---- Phase C: probe 27 neighbors, store rep, append pair lists ----
    {
        int v[27];
        #pragma unroll
        for (int o = 0; o < 27; ++o) {
            int x = px + o / 9 - 1;
            int y = py + (o / 3) % 3 - 1;
            int z = pz + o % 3 - 1;
            v[o] = active ? ws_i[(x * GRID_B + y) * GRID_B + z] : 0;
        }
        if (active) ws_i[REP_I + tid] = n - v[13];     // own voxel always occupied
        unsigned long long* lists = (unsigned long long*)(ws_i + LISTS_I);
        #pragma unroll
        for (int o = 0; o < 27; ++o) {
            if (o == 13) continue;
            bool hit = active && (v[o] >= 1);
            unsigned long long m = __ballot(hit);
            if (m != 0ull) {
                int ldr = (int)__ffsll((unsigned long long)m) - 1;
                unsigned base = 0;
                if (lane == ldr)
                    base = (unsigned)__hip_atomic_fetch_add(
                        ws_i + CNT_I + o * LSTR, (int)__popcll(m), AR, SC);
                base = (unsigned)__shfl((int)base, ldr);
                if (hit) {
                    int slot = (int)base + (int)__popcll(m & ((1ull << lane) - 1ull));
                    if (slot < N_CAP)
                        lists[o * N_CAP + slot] =
                            ((unsigned long long)(unsigned)(n - v[o]) << 32) |
                            (unsigned)tid;
                }
            }
        }
    }
    gbar(ws_i, 3);

    // ---- Phase D: center contribution, plain stores (initializes out) ----
    {
        const int cout = threadIdx.x & 31;
        float wreg[32];
        #pragma unroll
        for (int c = 0; c < 32; ++c) wreg[c] = w[13 * 1024 + c * 32 + cout];
        const int* __restrict__ rep = ws_i + REP_I;
        const int n32 = n * 32;
        for (int u = tid; u < n32; u += NT) {          // cout invariant (NT%32==0)
            int r = rep[u >> 5];
            const float4* __restrict__ f4p = (const float4*)(feat + r * C);
            float acc = 0.0f;
            #pragma unroll
            for (int k8 = 0; k8 < 8; ++k8) {
                float4 fv = f4p[k8];
                acc = fmaf(fv.x, wreg[4 * k8 + 0], acc);
                acc = fmaf(fv.y, wreg[4 * k8 + 1], acc);
                acc = fmaf(fv.z, wreg[4 * k8 + 2], acc);
                acc = fmaf(fv.w, wreg[4 * k8 + 3], acc);
            }
            out[u] = acc;
        }
    }
    gbar(ws_i, 4);

    // ---- Phase E: drain the 26 offset lists ----
    {
        int counts[27];
        int total_chunks = 0;
        #pragma unroll
        for (int o = 0; o < 27; ++o) {
            int c0 = (o == 13) ? 0 : ws_i[CNT_I + o * LSTR];
            c0 = min(c0, N_CAP);
            counts[o] = c0;
            total_chunks += (c0 + 15) >> 4;
        }
        const unsigned long long* __restrict__ lists =
            (const unsigned long long*)(ws_i + LISTS_I);
        const int wave_id = tid >> 6;
        const int n_waves = NT >> 6;                   // 4096
        const int cout = lane & 31;
        const int half = lane >> 5;

        for (int f = wave_id; f < total_chunks; f += n_waves) {
            int o = 0, rem = f;
            while (rem >= ((counts[o] + 15) >> 4)) {   // wave-uniform scan
                rem -= (counts[o] + 15) >> 4;
                ++o;
            }
            int cbase = rem * 16;
            int npair = min(16, counts[o] - cbase);

            float wreg[32];
            #pragma unroll
            for (int c = 0; c < 32; ++c) wreg[c] = w[o * 1024 + c * 32 + cout];

            unsigned long long e = 0ull;
            if (lane < npair) e = lists[o * N_CAP + cbase + lane];
            int j_i  = (int)(e >> 32);
            int pt_i = (int)(e & 0xffffffffu);

            for (int i = 0; 2 * i < npair; ++i) {
                int src = 2 * i + half;
                int pt = __shfl(pt_i, src);
                int j  = __shfl(j_i, src);
                if (src < npair) {
                    const float4* __restrict__ f4p = (const float4*)(feat + j * C);
                    float acc = 0.0f;
                    #pragma unroll
                    for (int k8 = 0; k8 < 8; ++k8) {
                        float4 fv = f4p[k8];
                        acc = fmaf(fv.x, wreg[4 * k8 + 0], acc);
                        acc = fmaf(fv.y, wreg[4 * k8 + 1], acc);
                        acc = fmaf(fv.z, wreg[4 * k8 + 2], acc);
                        acc = fmaf(fv.w, wreg[4 * k8 + 3], acc);
                    }
                    atomicAdd(&out[pt * C + cout], acc);
                }
            }
        }
    }
}

extern "C" void kernel_launch(void* const* d_in, const int* in_sizes, int n_in,
                              void* d_out, int out_size, void* d_ws, size_t ws_size,
                              hipStream_t stream) {
    const float* features = (const float*)d_in[0];
    const int*   positions = (const int*)d_in[1];
    const float* weight = (const float*)d_in[2];
    float* out = (float*)d_out;
    const int n = in_sizes[0] / C;     // 100000

    fused_kernel<<<NBLK, NTHR, 0, stream>>>(features, positions, weight,
                                            (int*)d_ws, out, n);
}

// Round 5
// 130.363 us; speedup vs baseline: 6.5853x; 6.5853x over previous
//
#include <hip/hip_runtime.h>

// Submanifold sparse conv — 3 dispatches (R4 lesson: grid barriers on MI355X
// cost per-XCD L2 wb/inv storms; never again).
//   1. hipMemsetAsync grid to 0
//   2. build_grid: atomicMax(grid[key], n-i)   (empty=0; max(n-i) == min index,
//      matching reference's stable-argsort duplicate resolution)
//   3. conv: block = 64 points, block-local rulebook in LDS:
//        P1 probe: 64x27 probes over 256 threads (high MLP), hits appended to
//           per-offset LDS lists via LDS atomics (R2 lesson: global same-line
//           atomics serialize at ~2ns/op; LDS ones don't)
//        P2 center: W13 column in 32 VGPRs, float4 gathers, plain writes to
//           LDS acc tile [64][32] (doubles as acc init)
//        P3 drain: wave w handles offsets o=w,w+4,...; W[o] column loaded ONCE
//           per (block,offset) into 32 VGPRs (weight L1 traffic 900MB -> 170MB
//           vs R1), half-wave per pair, float4 feature broadcasts, ds_add_f32
//           into acc tile. All out-writes are block-owned -> no global atomics.
//        P4 write-out: coalesced plain stores.

#define GRID_B 130
#define GRID_CELLS 2197000
#define C 32
#define NTHR 256
#define PTS 64                  // points per block
#define CAP 24                  // per-offset list cap (Poisson lambda~3.1; P(>24)~1e-13)

__global__ void build_grid_kernel(const int* __restrict__ pos,
                                  int* __restrict__ grid, int n) {
    int i = blockIdx.x * blockDim.x + threadIdx.x;
    if (i >= n) return;
    int x = pos[3 * i + 0] + 1;
    int y = pos[3 * i + 1] + 1;
    int z = pos[3 * i + 2] + 1;
    atomicMax(&grid[(x * GRID_B + y) * GRID_B + z], n - i);
}

__global__ __launch_bounds__(NTHR)
void conv_kernel(const float* __restrict__ feat,
                 const int* __restrict__ pos,
                 const float* __restrict__ w,
                 const int* __restrict__ grid,
                 float* __restrict__ out, int n) {
    __shared__ int   s_cnt[27];
    __shared__ int   s_list[27][CAP];     // packed (pt_local<<17) | j
    __shared__ int   s_rep[PTS];          // center neighbor (min-dup index)
    __shared__ float s_acc[PTS][C];       // 8 KB accumulator tile

    const int tid = threadIdx.x;
    const int pt_base = blockIdx.x * PTS;

    if (tid < 27) s_cnt[tid] = 0;
    __syncthreads();

    // ---- P1: probe 64 pts x 27 offsets (7 independent probes per thread) ----
    for (int t = tid; t < PTS * 27; t += NTHR) {
        int pl = t / 27;                 // const-div -> magic mul
        int o  = t - pl * 27;
        int pt = pt_base + pl;
        if (pt < n) {
            int x = pos[3 * pt + 0] + (o / 9) - 1 + 1;
            int y = pos[3 * pt + 1] + ((o / 3) % 3) - 1 + 1;
            int z = pos[3 * pt + 2] + (o % 3) - 1 + 1;
            int v = grid[(x * GRID_B + y) * GRID_B + z];
            if (o == 13) {
                s_rep[pl] = n - v;       // own voxel always occupied
            } else if (v >= 1) {         // neighbor present (~1.2 of 26)
                int slot = atomicAdd(&s_cnt[o], 1);
                if (slot < CAP) s_list[o][slot] = (pl << 17) | (n - v);
            }
        }
    }
    __syncthreads();

    // ---- P2: center contribution -> initializes s_acc (plain writes) ----
    {
        const int cout = tid & 31;
        float wreg[32];
        #pragma unroll
        for (int c = 0; c < 32; ++c) wreg[c] = w[13 * 1024 + c * 32 + cout];
        for (int u = tid; u < PTS * C; u += NTHR) {    // u&31 == cout (NTHR%32==0)
            int pl = u >> 5;
            if (pt_base + pl < n) {
                const float4* __restrict__ f4 = (const float4*)(feat + (size_t)s_rep[pl] * C);
                float acc = 0.0f;
                #pragma unroll
                for (int k = 0; k < 8; ++k) {
                    float4 fv = f4[k];
                    acc = fmaf(fv.x, wreg[4 * k + 0], acc);
                    acc = fmaf(fv.y, wreg[4 * k + 1], acc);
                    acc = fmaf(fv.z, wreg[4 * k + 2], acc);
                    acc = fmaf(fv.w, wreg[4 * k + 3], acc);
                }
                s_acc[pl][cout] = acc;
            }
        }
    }
    __syncthreads();

    // ---- P3: drain per-offset lists; W[o] column amortized over the list ----
    {
        const int wv = tid >> 6;          // wave 0..3
        const int lane = tid & 63;
        const int cout = lane & 31;
        const int half = lane >> 5;
        for (int o = wv; o < 27; o += 4) {
            if (o == 13) continue;
            int cnt = min(s_cnt[o], CAP);
            if (cnt == 0) continue;
            float wreg[32];
            #pragma unroll
            for (int c = 0; c < 32; ++c) wreg[c] = w[o * 1024 + c * 32 + cout];
            for (int e = half; e < cnt; e += 2) {      // 2 pairs per wave iter
                int packed = s_list[o][e];             // LDS same-addr broadcast
                int pl = packed >> 17;
                int j  = packed & 0x1FFFF;
                const float4* __restrict__ f4 = (const float4*)(feat + (size_t)j * C);
                float acc = 0.0f;
                #pragma unroll
                for (int k = 0; k < 8; ++k) {
                    float4 fv = f4[k];
                    acc = fmaf(fv.x, wreg[4 * k + 0], acc);
                    acc = fmaf(fv.y, wreg[4 * k + 1], acc);
                    acc = fmaf(fv.z, wreg[4 * k + 2], acc);
                    acc = fmaf(fv.w, wreg[4 * k + 3], acc);
                }
                atomicAdd(&s_acc[pl][cout], acc);      // ds_add_f32, banks 0..31 clean
            }
        }
    }
    __syncthreads();

    // ---- P4: coalesced write-out (block owns its 64 points exclusively) ----
    {
        const int base = pt_base * C;
        const int lim = n * C - base;                  // last block: exactly 1024
        for (int u = tid; u < PTS * C && u < lim; u += NTHR)
            out[base + u] = s_acc[u >> 5][u & 31];
    }
}

extern "C" void kernel_launch(void* const* d_in, const int* in_sizes, int n_in,
                              void* d_out, int out_size, void* d_ws, size_t ws_size,
                              hipStream_t stream) {
    const float* features = (const float*)d_in[0];
    const int*   positions = (const int*)d_in[1];
    const float* weight = (const float*)d_in[2];
    float* out = (float*)d_out;
    const int n = in_sizes[0] / C;       // 100000

    int* grid = (int*)d_ws;
    hipMemsetAsync(grid, 0, (size_t)GRID_CELLS * sizeof(int), stream);

    build_grid_kernel<<<(n + 255) / 256, 256, 0, stream>>>(positions, grid, n);

    conv_kernel<<<(n + PTS - 1) / PTS, NTHR, 0, stream>>>(features, positions, weight,
                                                          grid, out, n);
}